// Round 2
// baseline (605.065 us; speedup 1.0000x reference)
//
#include <hip/hip_runtime.h>
#include <cstdint>

#define NB 32768        // rows per entity
#define HH 512          // hidden dim

typedef __attribute__((ext_vector_type(8))) _Float16 f16x8;
typedef __attribute__((ext_vector_type(4))) float f32x4;
typedef __attribute__((ext_vector_type(4))) unsigned short us4v;

__device__ __forceinline__ unsigned short f2h(float f) {
  _Float16 h = (_Float16)f;
  return __builtin_bit_cast(unsigned short, h);
}
__device__ __forceinline__ float h2f(unsigned short u) {
  return (float)__builtin_bit_cast(_Float16, u);
}

__device__ __forceinline__ void gl_lds16(const void* g, void* l) {
  __builtin_amdgcn_global_load_lds(
      (const __attribute__((address_space(1))) unsigned int*)g,
      (__attribute__((address_space(3))) unsigned int*)l, 16, 0, 0);
}

__device__ __forceinline__ float wred(float v) {
#pragma unroll
  for (int off = 32; off > 0; off >>= 1) v += __shfl_xor(v, off);
  return v;
}

__device__ __forceinline__ float softplusf(float x) {
  return fmaxf(x, 0.f) + log1pf(expf(-fabsf(x)));
}

// ---------- weights -> fp16, zero rho accumulator ----------
__global__ __launch_bounds__(256) void prep_w(
    const float* __restrict__ W1, const float* __restrict__ W2,
    const float* __restrict__ Wv, const float* __restrict__ Wt,
    unsigned short* __restrict__ W1h, unsigned short* __restrict__ W2h,
    unsigned short* __restrict__ Wvh, unsigned short* __restrict__ Wth,
    float* __restrict__ rho) {
  int i = blockIdx.x * 256 + threadIdx.x;  // grid covers exactly 917504
  if (i < 98304) rho[i] = 0.f;
  if (i < 262144) W1h[i] = f2h(W1[i]);
  else if (i < 524288) W2h[i - 262144] = f2h(W2[i - 262144]);
  else if (i < 655360) Wvh[i - 524288] = f2h(Wv[i - 524288]);
  else Wth[i - 655360] = f2h(Wt[i - 655360]);
}

// ---------- GEMM-0: Out = fp16(relu(A_f32 @ W_f16^T + bias)) ----------
// A is (M x 512) fp32, staged directly to LDS as fp32, converted after ds_read.
__global__ __launch_bounds__(256) void gemm0_k(
    const float* __restrict__ A, const unsigned short* __restrict__ W,
    const float* __restrict__ bias, unsigned short* __restrict__ Out) {
  __shared__ float Af[128 * 64];           // 32 KB
  __shared__ unsigned short Bs[128 * 64];  // 16 KB
  const int tid = threadIdx.x, lane = tid & 63, w = tid >> 6;
  const long m0 = (long)blockIdx.y * 128;
  const int n0 = blockIdx.x * 128;
  const int wr = (w >> 1) * 64, wc = (w & 1) * 64;

  // A staging (fp32): lane -> row w*32+(lane>>4), col (lane&15)*4 floats (16B)
  const int arow = w * 32 + (lane >> 4), acol = (lane & 15) * 4;
  const float* Ag = A + (long)(m0 + arow) * HH + acol;
  float* Al = Af + arow * 64 + acol;
  // B staging (fp16): lane -> row w*32+(lane>>3), col (lane&7)*8 halves (16B)
  const int brow = w * 32 + (lane >> 3), bcol = (lane & 7) * 8;
  const unsigned short* Bg = W + (long)(n0 + brow) * HH + bcol;
  unsigned short* Bl = Bs + brow * 64 + bcol;

  f32x4 acc[4][4] = {};
  for (int kb = 0; kb < 8; ++kb) {
    const int ko = kb * 64;
#pragma unroll
    for (int q = 0; q < 8; ++q)
      gl_lds16(Ag + (long)(4 * q) * HH + ko, Al + (4 * q) * 64);
#pragma unroll
    for (int q = 0; q < 4; ++q)
      gl_lds16(Bg + (long)(8 * q) * HH + ko, Bl + (8 * q) * 64);
    __syncthreads();
#pragma unroll
    for (int ks = 0; ks < 2; ++ks) {
      const int kcol = ks * 32 + (lane >> 4) * 8;
      f16x8 af[4], bf[4];
#pragma unroll
      for (int i = 0; i < 4; ++i) {
        const float* ap = Af + (wr + i * 16 + (lane & 15)) * 64 + kcol;
        f32x4 a0 = *(const f32x4*)ap;
        f32x4 a1 = *(const f32x4*)(ap + 4);
        f16x8 t;
        t[0] = (_Float16)a0[0]; t[1] = (_Float16)a0[1];
        t[2] = (_Float16)a0[2]; t[3] = (_Float16)a0[3];
        t[4] = (_Float16)a1[0]; t[5] = (_Float16)a1[1];
        t[6] = (_Float16)a1[2]; t[7] = (_Float16)a1[3];
        af[i] = t;
        bf[i] = *(const f16x8*)(Bs + (wc + i * 16 + (lane & 15)) * 64 + kcol);
      }
#pragma unroll
      for (int i = 0; i < 4; ++i)
#pragma unroll
        for (int j = 0; j < 4; ++j)
          acc[i][j] = __builtin_amdgcn_mfma_f32_16x16x32_f16(af[i], bf[j], acc[i][j], 0, 0, 0);
    }
    __syncthreads();
  }

  const int cg = lane >> 4, cl = lane & 15;
#pragma unroll
  for (int mi = 0; mi < 4; ++mi) {
    const long row0 = m0 + wr + mi * 16 + cg * 4;
#pragma unroll
    for (int ni = 0; ni < 4; ++ni) {
      const int col = n0 + wc + ni * 16 + cl;
      const float bcol = bias[col];
#pragma unroll
      for (int r = 0; r < 4; ++r)
        Out[(row0 + r) * HH + col] = f2h(fmaxf(acc[mi][ni][r] + bcol, 0.f));
    }
  }
}

// ---------- fp16-A GEMM: C = A(Mx512,f16) @ W(Nx512,f16)^T ----------
// MODE 1: v = C+bias+Xres; OutH=f16(v) (ld HH); rho_base[row] += v . wsel  (E stage)
// MODE 2: OutH = f16(C+bias), stride ldo                                    (U heads)
// MODE 3: OutF = C+bias (fp32), stride ldo                                  (theta head)
template <int MODE>
__global__ __launch_bounds__(256) void gemm16_k(
    const unsigned short* __restrict__ A, const unsigned short* __restrict__ W,
    const float* __restrict__ bias, const float* __restrict__ Xres,
    const float* __restrict__ wsel, float* __restrict__ rho_base,
    unsigned short* __restrict__ OutH, float* __restrict__ OutF, int ldo) {
  __shared__ unsigned short As[128 * 64];
  __shared__ unsigned short Bs[128 * 64];
  const int tid = threadIdx.x, lane = tid & 63, w = tid >> 6;
  const long m0 = (long)blockIdx.y * 128;
  const int n0 = blockIdx.x * 128;
  const int wr = (w >> 1) * 64, wc = (w & 1) * 64;

  const int srow = w * 32 + (lane >> 3), scol = (lane & 7) * 8;
  const unsigned short* Ag = A + (long)(m0 + srow) * HH + scol;
  const unsigned short* Bg = W + (long)(n0 + srow) * HH + scol;
  unsigned short* Al = As + srow * 64 + scol;
  unsigned short* Bl = Bs + srow * 64 + scol;

  f32x4 acc[4][4] = {};
  for (int kb = 0; kb < 8; ++kb) {
    const int ko = kb * 64;
#pragma unroll
    for (int q = 0; q < 4; ++q) {
      gl_lds16(Ag + (long)(8 * q) * HH + ko, Al + (8 * q) * 64);
      gl_lds16(Bg + (long)(8 * q) * HH + ko, Bl + (8 * q) * 64);
    }
    __syncthreads();
#pragma unroll
    for (int ks = 0; ks < 2; ++ks) {
      const int kcol = ks * 32 + (lane >> 4) * 8;
      f16x8 af[4], bf[4];
#pragma unroll
      for (int i = 0; i < 4; ++i) {
        af[i] = *(const f16x8*)(As + (wr + i * 16 + (lane & 15)) * 64 + kcol);
        bf[i] = *(const f16x8*)(Bs + (wc + i * 16 + (lane & 15)) * 64 + kcol);
      }
#pragma unroll
      for (int i = 0; i < 4; ++i)
#pragma unroll
        for (int j = 0; j < 4; ++j)
          acc[i][j] = __builtin_amdgcn_mfma_f32_16x16x32_f16(af[i], bf[j], acc[i][j], 0, 0, 0);
    }
    __syncthreads();
  }

  const int cg = lane >> 4, cl = lane & 15;
  float drow[4][4] = {};
#pragma unroll
  for (int mi = 0; mi < 4; ++mi) {
    const long row0 = m0 + wr + mi * 16 + cg * 4;
#pragma unroll
    for (int ni = 0; ni < 4; ++ni) {
      const int col = n0 + wc + ni * 16 + cl;
      const float bcol = bias[col];
      float wv = 0.f;
      if constexpr (MODE == 1) wv = wsel[col];
#pragma unroll
      for (int r = 0; r < 4; ++r) {
        const long row = row0 + r;
        float v = acc[mi][ni][r] + bcol;
        if constexpr (MODE == 1) {
          v += Xres[row * HH + col];
          OutH[row * HH + col] = f2h(v);
          drow[mi][r] += v * wv;  // exact fp32 rho/delta_rho dot
        } else if constexpr (MODE == 2) {
          OutH[row * (long)ldo + col] = f2h(v);
        } else {
          OutF[row * (long)ldo + col] = v;
        }
      }
    }
  }
  if constexpr (MODE == 1) {
#pragma unroll
    for (int mi = 0; mi < 4; ++mi)
#pragma unroll
      for (int r = 0; r < 4; ++r) {
        float s = drow[mi][r];
        s += __shfl_xor(s, 1);
        s += __shfl_xor(s, 2);
        s += __shfl_xor(s, 4);
        s += __shfl_xor(s, 8);
        if (cl == 0) atomicAdd(&rho_base[m0 + wr + mi * 16 + cg * 4 + r], s);
      }
  }
}

// ---------- Givens chain pass as a wave-parallel linear scan ----------
// v[4] per lane = positions 4*lane..4*lane+3 of a 256-vector.
// Rotations t=0..255 at (t,(t+1)%256): carry K_{t+1}=s_t*K_t+c_t*v_{t+1},
// out[t]=c_t*K_t-s_t*v_{t+1}; wrap rotation t=255 fixed up in closed form.
__device__ __forceinline__ void givens_pass(float v[4], const float c[4],
                                            const float s[4], int lane) {
  float vn3 = __shfl_down(v[0], 1);  // neighbor lane's first element
  float A = 1.f, Bc = 0.f;           // local transform composition
#pragma unroll
  for (int k = 0; k < 4; ++k) {
    float vnext = (k < 3) ? v[k + 1] : vn3;
    bool skip = (lane == 63) && (k == 3);  // t==255 handled in fixup
    if (!skip) {
      Bc = s[k] * Bc + c[k] * vnext;
      A = s[k] * A;
    }
  }
  float iA = A, iB = Bc;  // inclusive scan (compose with earlier lanes)
#pragma unroll
  for (int off = 1; off < 64; off <<= 1) {
    float pA = __shfl_up(iA, off);
    float pB = __shfl_up(iB, off);
    if (lane >= off) { iB = iA * pB + iB; iA = iA * pA; }
  }
  float eA = __shfl_up(iA, 1);
  float eB = __shfl_up(iB, 1);
  if (lane == 0) { eA = 1.f; eB = 0.f; }
  float v0g = __shfl(v[0], 0);
  float K = eA * v0g + eB;  // K at t = 4*lane
  float out[4];
#pragma unroll
  for (int k = 0; k < 4; ++k) {
    float vnext = (k < 3) ? v[k + 1] : vn3;
    bool skip = (lane == 63) && (k == 3);
    if (!skip) {
      out[k] = c[k] * K - s[k] * vnext;
      K = s[k] * K + c[k] * vnext;
    } else out[k] = 0.f;
  }
  float K255 = __shfl(K, 63);
  float c255 = __shfl(c[3], 63);
  float s255 = __shfl(s[3], 63);
  float o0 = __shfl(out[0], 0);
  if (lane == 63) out[3] = c255 * K255 - s255 * o0;
  if (lane == 0) out[0] = s255 * K255 + c255 * o0;
  v[0] = out[0]; v[1] = out[1]; v[2] = out[2]; v[3] = out[3];
}

// ---------- final per-row kernel: one wave per row ----------
__global__ __launch_bounds__(256) void final_k(
    const unsigned short* __restrict__ Uh, const unsigned short* __restrict__ Ut,
    const float* __restrict__ TH, const float* __restrict__ rho_raw,
    const float* __restrict__ sim, const float* __restrict__ bre,
    const float* __restrict__ brr, const float* __restrict__ ga_rho,
    const float* __restrict__ gb_rho, const float* __restrict__ ga_phi,
    const float* __restrict__ gb_phi, float* __restrict__ out) {
  const int lane = threadIdx.x & 63;
  const int b = blockIdx.x * 4 + (threadIdx.x >> 6);

  us4v h4 = *(const us4v*)(Uh + (long)b * 256 + lane * 4);
  us4v t4 = *(const us4v*)(Ut + (long)b * 256 + lane * 4);
  const float* th = TH + (long)b * 512;
  f32x4 tA = *(const f32x4*)(th + lane * 4);
  f32x4 tB = *(const f32x4*)(th + 256 + lane * 4);

  float vh[4], vt[4];
#pragma unroll
  for (int k = 0; k < 4; ++k) { vh[k] = h2f(h4[k]); vt[k] = h2f(t4[k]); }

  const float PI_F = 3.14159265358979f;
  float cA[4], sA[4], cB[4], sB[4];
#pragma unroll
  for (int k = 0; k < 4; ++k) {
    float a1 = PI_F * tanhf(tA[k]);
    sincosf(a1, &sA[k], &cA[k]);
    float a2 = PI_F * tanhf(tB[k]);
    sincosf(a2, &sB[k], &cB[k]);
  }

  float ssq = wred(vh[0] * vh[0] + vh[1] * vh[1] + vh[2] * vh[2] + vh[3] * vh[3]);
  float invh = 1.f / (sqrtf(ssq) + 1e-8f);
  float u[4], v[4];
#pragma unroll
  for (int k = 0; k < 4; ++k) { u[k] = vh[k] * invh; v[k] = u[k]; }

  givens_pass(v, cA, sA, lane);  // rotations 0..255
  givens_pass(v, cB, sB, lane);  // rotations 256..511

  float ssr = wred(v[0] * v[0] + v[1] * v[1] + v[2] * v[2] + v[3] * v[3]);
  float invr = 1.f / (sqrtf(ssr) + 1e-8f);
  float ur[4];
#pragma unroll
  for (int k = 0; k < 4; ++k) ur[k] = v[k] * invr;

  float dt = wred(u[0] * ur[0] + u[1] * ur[1] + u[2] * ur[2] + u[3] * ur[3]);
  dt = fminf(fmaxf(dt, -1.f + 1e-8f), 1.f - 1e-8f);
  float omega = acosf(dt);
  float sino = sinf(omega);
  float sb = sim[b];
  float gphi = 1.f / (1.f + expf(-(ga_phi[0] * sb + gb_phi[0])));
  float s1, s2;
  if (omega > 0.001f) {
    s1 = sinf((1.f - gphi) * omega) / (sino + 1e-8f);
    s2 = sinf(gphi * omega) / (sino + 1e-8f);
  } else {
    s1 = 1.f - gphi;
    s2 = gphi;
  }
  float up[4];
#pragma unroll
  for (int k = 0; k < 4; ++k) up[k] = s1 * u[k] + s2 * ur[k];
  float ssp = wred(up[0] * up[0] + up[1] * up[1] + up[2] * up[2] + up[3] * up[3]);
  float invp = 1.f / (sqrtf(ssp) + 1e-8f);
  float sst = wred(vt[0] * vt[0] + vt[1] * vt[1] + vt[2] * vt[2] + vt[3] * vt[3]);
  float invt = 1.f / (sqrtf(sst) + 1e-8f);
  float dp = wred(up[0] * vt[0] + up[1] * vt[1] + up[2] * vt[2] + up[3] * vt[3]) * invp * invt;

  float rh = fminf(fmaxf(softplusf(rho_raw[b] + bre[0]), 0.f), 9.f);
  float rt = fminf(fmaxf(softplusf(rho_raw[NB + b] + bre[0]), 0.f), 9.f);
  float dR = rho_raw[2 * NB + b] + brr[0];
  float grho = 1.f / (1.f + expf(-(ga_rho[0] * sb + gb_rho[0])));
  float rp = fminf(fmaxf(rh + dR * grho, 0.f), 9.f);
  float score = -coshf(rp) * coshf(rt) + sinhf(rp) * sinhf(rt) * dp;
  if (lane == 0) out[b] = score;
}

extern "C" void kernel_launch(void* const* d_in, const int* in_sizes, int n_in,
                              void* d_out, int out_size, void* d_ws, size_t ws_size,
                              hipStream_t stream) {
  (void)in_sizes; (void)n_in;
  const float* ent = (const float*)d_in[0];
  const float* rel = (const float*)d_in[1];
  const float* lab = (const float*)d_in[2];
  const float* sim = (const float*)d_in[3];
  const float* Wv = (const float*)d_in[4];
  const float* bv = (const float*)d_in[5];
  const float* Wre = (const float*)d_in[6];
  const float* bre = (const float*)d_in[7];
  const float* Wrr = (const float*)d_in[8];
  const float* brr = (const float*)d_in[9];
  const float* Wt = (const float*)d_in[10];
  const float* bt = (const float*)d_in[11];
  const float* ga_rho = (const float*)d_in[12];
  const float* gb_rho = (const float*)d_in[13];
  const float* ga_phi = (const float*)d_in[14];
  const float* gb_phi = (const float*)d_in[15];
  const float* W1 = (const float*)d_in[16];
  const float* b1 = (const float*)d_in[17];
  const float* W2 = (const float*)d_in[18];
  const float* b2 = (const float*)d_in[19];

  // workspace layout (162.1 MiB total)
  const size_t NEEDED = 170000384ULL;
  if (ws_size < NEEDED) {  // clean diagnostic failure instead of OOB fault
    (void)hipMemsetAsync(d_out, 0, (size_t)out_size * sizeof(float), stream);
    return;
  }
  char* ws = (char*)d_ws;
  float* TH = (float*)ws;                                   // 64 MB  (NB x 512 f32)
  unsigned short* Uh = (unsigned short*)(ws + 67108864);    // 16 MB  (NB x 256 f16)
  unsigned short* Ut = (unsigned short*)(ws + 83886080);    // 16 MB
  unsigned short* Tb = (unsigned short*)(ws + 100663296);   // 32 MB  (NB x 512 f16)
  unsigned short* Eb = (unsigned short*)(ws + 134217728);   // 32 MB
  float* rho_raw = (float*)(ws + 167772160);                // 384 KB (3*NB f32)
  unsigned short* W1h = (unsigned short*)(ws + 168165376);  // 512 KB
  unsigned short* W2h = (unsigned short*)(ws + 168689664);  // 512 KB
  unsigned short* Wvh = (unsigned short*)(ws + 169213952);  // 256 KB
  unsigned short* Wth = (unsigned short*)(ws + 169476096);  // 512 KB

  prep_w<<<dim3(3584), dim3(256), 0, stream>>>(W1, W2, Wv, Wt, W1h, W2h, Wvh, Wth, rho_raw);

  // ---- entity h (ent_embed) ----
  gemm0_k<<<dim3(4, 256), dim3(256), 0, stream>>>(ent, W1h, b1, Tb);
  gemm16_k<1><<<dim3(4, 256), dim3(256), 0, stream>>>(
      Tb, W2h, b2, ent, Wre, rho_raw, Eb, nullptr, HH);
  gemm16_k<2><<<dim3(2, 256), dim3(256), 0, stream>>>(
      Eb, Wvh, bv, nullptr, nullptr, nullptr, Uh, nullptr, 256);

  // ---- entity t (ent_label) ----
  gemm0_k<<<dim3(4, 256), dim3(256), 0, stream>>>(lab, W1h, b1, Tb);
  gemm16_k<1><<<dim3(4, 256), dim3(256), 0, stream>>>(
      Tb, W2h, b2, lab, Wre, rho_raw + NB, Eb, nullptr, HH);
  gemm16_k<2><<<dim3(2, 256), dim3(256), 0, stream>>>(
      Eb, Wvh, bv, nullptr, nullptr, nullptr, Ut, nullptr, 256);

  // ---- entity r (rel_embed) ----
  gemm0_k<<<dim3(4, 256), dim3(256), 0, stream>>>(rel, W1h, b1, Tb);
  gemm16_k<1><<<dim3(4, 256), dim3(256), 0, stream>>>(
      Tb, W2h, b2, rel, Wrr, rho_raw + 2 * NB, Eb, nullptr, HH);
  gemm16_k<3><<<dim3(4, 256), dim3(256), 0, stream>>>(
      Eb, Wth, bt, nullptr, nullptr, nullptr, nullptr, TH, HH);

  final_k<<<dim3(8192), dim3(256), 0, stream>>>(
      Uh, Ut, TH, rho_raw, sim, bre, brr, ga_rho, gb_rho, ga_phi, gb_phi, (float*)d_out);
}

// Round 4
// 594.787 us; speedup vs baseline: 1.0173x; 1.0173x over previous
//
#include <hip/hip_runtime.h>
#include <cstdint>

#define NB 32768        // rows per entity
#define HH 512          // hidden dim

typedef __attribute__((ext_vector_type(8))) _Float16 f16x8;
typedef __attribute__((ext_vector_type(4))) float f32x4;
typedef __attribute__((ext_vector_type(4))) unsigned short us4v;

static __device__ __forceinline__ unsigned short f2h(float f) {
  _Float16 h = (_Float16)f;
  return __builtin_bit_cast(unsigned short, h);
}
static __device__ __forceinline__ float h2f(unsigned short u) {
  return (float)__builtin_bit_cast(_Float16, u);
}
static __device__ __forceinline__ void gl_lds16(const void* g, void* l) {
  __builtin_amdgcn_global_load_lds(
      (const __attribute__((address_space(1))) unsigned int*)g,
      (__attribute__((address_space(3))) unsigned int*)l, 16, 0, 0);
}
static __device__ __forceinline__ float wred(float v) {
#pragma unroll
  for (int off = 32; off > 0; off >>= 1) v += __shfl_xor(v, off);
  return v;
}
static __device__ __forceinline__ float sigm(float x) { return 1.f / (1.f + __expf(-x)); }
static __device__ __forceinline__ float tanh_fast(float x) {
  return 1.f - 2.f / (__expf(2.f * x) + 1.f);
}
static __device__ __forceinline__ float softplus_fast(float x) {
  return fmaxf(x, 0.f) + log1pf(__expf(-fabsf(x)));
}

// ================= prep: weight casts + w2re/w2rr + rho consts + rho zero ==========
__global__ __launch_bounds__(256) void prep_k(
    const float* __restrict__ W1, const float* __restrict__ Wv,
    const float* __restrict__ Wt, const float* __restrict__ Wre,
    const float* __restrict__ Wrr, const float* __restrict__ b2,
    const float* __restrict__ W2,
    unsigned short* __restrict__ W1h, unsigned short* __restrict__ Wvh,
    unsigned short* __restrict__ Wth, float* __restrict__ rho_raw,
    float* __restrict__ w2re, float* __restrict__ w2rr, float* __restrict__ rho_c) {
  __shared__ float red[4];
  const int bx = blockIdx.x, t = threadIdx.x;
  if (bx < 2560) {
    int i = bx * 256 + t;            // 0 .. 655359
    if (i < 98304) rho_raw[i] = 0.f;
    if (i < 262144) W1h[i] = f2h(W1[i]);
    else if (i < 393216) Wvh[i - 262144] = f2h(Wv[i - 262144]);
    else Wth[i - 393216] = f2h(Wt[i - 393216]);
  } else if (bx < 2562) {
    // w2sel[k] = sum_j wsel[j] * W2[j,k]   (fp32 exact, coalesced over k)
    const float* ws = (bx == 2560) ? Wre : Wrr;
    float* wd = (bx == 2560) ? w2re : w2rr;
    float a0 = 0.f, a1 = 0.f;
    for (int j = 0; j < 512; ++j) {
      float wv = ws[j];
      a0 += wv * W2[j * 512 + t];
      a1 += wv * W2[j * 512 + t + 256];
    }
    wd[t] = a0;
    wd[t + 256] = a1;
  } else {
    // rho_c[0] = b2.wre ; rho_c[1] = b2.wrr
    const float* ws = (bx == 2562) ? Wre : Wrr;
    float p = b2[t] * ws[t] + b2[t + 256] * ws[t + 256];
    p = wred(p);
    if ((t & 63) == 0) red[t >> 6] = p;
    __syncthreads();
    if (t == 0) rho_c[bx - 2562] = red[0] + red[1] + red[2] + red[3];
  }
}

// ================= GEMM1 (batched 3 entities): T = relu(X@W1^T + b1) ===============
// Also accumulates rho_raw[row] = X.wsel (fp32, from staged fp32 A; one wave-column)
//                              + T.w2sel (fp32, epilogue; all blocks)
__global__ __launch_bounds__(256, 3) void gemm1_k(
    const float* __restrict__ x0, const float* __restrict__ x1,
    const float* __restrict__ x2, const unsigned short* __restrict__ W1h,
    const float* __restrict__ b1, const float* __restrict__ wre,
    const float* __restrict__ wrr, const float* __restrict__ w2re,
    const float* __restrict__ w2rr, unsigned short* __restrict__ Tbig,
    float* __restrict__ rho_raw) {
  __shared__ float Af[128 * 64];           // 32 KB
  __shared__ unsigned short Bs[128 * 64];  // 16 KB
  const int tid = threadIdx.x, lane = tid & 63, w = tid >> 6;
  const int by = blockIdx.y, ent = by >> 8;
  const long mloc = (long)(by & 255) * 128;
  const float* X = (ent == 0) ? x0 : (ent == 1) ? x1 : x2;
  const float* wsel = (ent < 2) ? wre : wrr;
  const float* w2sel = (ent < 2) ? w2re : w2rr;
  const int n0 = blockIdx.x * 128;
  // X.wsel must be accumulated ONCE per row: rows are shared by the two
  // column-waves (w&1), so gate to the wc==0 wave only. (R3 bug: 2x count.)
  const bool do_rx = (blockIdx.x == 0) && ((w & 1) == 0);
  const int wr = (w >> 1) * 64, wc = (w & 1) * 64;

  const int arow = w * 32 + (lane >> 4), acol = (lane & 15) * 4;
  const float* Ag = X + (mloc + arow) * HH + acol;
  float* Al = Af + arow * 64 + acol;
  const int brow = w * 32 + (lane >> 3), bcol = (lane & 7) * 8;
  const unsigned short* Bg = W1h + (long)(n0 + brow) * HH + bcol;
  unsigned short* Bl = Bs + brow * 64 + bcol;

  f32x4 acc[4][4] = {};
  float rx[4] = {0.f, 0.f, 0.f, 0.f};
  for (int kb = 0; kb < 8; ++kb) {
    const int ko = kb * 64;
#pragma unroll
    for (int q = 0; q < 8; ++q) gl_lds16(Ag + (long)(4 * q) * HH + ko, Al + (4 * q) * 64);
#pragma unroll
    for (int q = 0; q < 4; ++q) gl_lds16(Bg + (long)(8 * q) * HH + ko, Bl + (8 * q) * 64);
    __syncthreads();
#pragma unroll
    for (int ks = 0; ks < 2; ++ks) {
      const int kcol = ks * 32 + (lane >> 4) * 8;
      float wv[8];
      if (do_rx) {
        f32x4 wa = *(const f32x4*)(wsel + ko + kcol);
        f32x4 wb = *(const f32x4*)(wsel + ko + kcol + 4);
        wv[0] = wa[0]; wv[1] = wa[1]; wv[2] = wa[2]; wv[3] = wa[3];
        wv[4] = wb[0]; wv[5] = wb[1]; wv[6] = wb[2]; wv[7] = wb[3];
      }
      f16x8 af[4], bf[4];
#pragma unroll
      for (int i = 0; i < 4; ++i) {
        const float* ap = Af + (wr + i * 16 + (lane & 15)) * 64 + kcol;
        f32x4 a0 = *(const f32x4*)ap, a1 = *(const f32x4*)(ap + 4);
        f16x8 t;
        t[0] = (_Float16)a0[0]; t[1] = (_Float16)a0[1];
        t[2] = (_Float16)a0[2]; t[3] = (_Float16)a0[3];
        t[4] = (_Float16)a1[0]; t[5] = (_Float16)a1[1];
        t[6] = (_Float16)a1[2]; t[7] = (_Float16)a1[3];
        af[i] = t;
        if (do_rx) {
          rx[i] += a0[0] * wv[0] + a0[1] * wv[1] + a0[2] * wv[2] + a0[3] * wv[3] +
                   a1[0] * wv[4] + a1[1] * wv[5] + a1[2] * wv[6] + a1[3] * wv[7];
        }
        bf[i] = *(const f16x8*)(Bs + (wc + i * 16 + (lane & 15)) * 64 + kcol);
      }
#pragma unroll
      for (int i = 0; i < 4; ++i)
#pragma unroll
        for (int j = 0; j < 4; ++j)
          acc[i][j] = __builtin_amdgcn_mfma_f32_16x16x32_f16(af[i], bf[j], acc[i][j], 0, 0, 0);
    }
    __syncthreads();
  }

  const int cg = lane >> 4, cl = lane & 15;
  const long rbase = (long)ent * NB + mloc;
  float drow[4][4] = {};
#pragma unroll
  for (int mi = 0; mi < 4; ++mi) {
    const long row0 = rbase + wr + mi * 16 + cg * 4;
#pragma unroll
    for (int ni = 0; ni < 4; ++ni) {
      const int col = n0 + wc + ni * 16 + cl;
      const float bc = b1[col], w2v = w2sel[col];
#pragma unroll
      for (int r = 0; r < 4; ++r) {
        float v = fmaxf(acc[mi][ni][r] + bc, 0.f);
        Tbig[(row0 + r) * HH + col] = f2h(v);
        drow[mi][r] += v * w2v;
      }
    }
  }
#pragma unroll
  for (int mi = 0; mi < 4; ++mi)
#pragma unroll
    for (int r = 0; r < 4; ++r) {
      float s = drow[mi][r];
      s += __shfl_xor(s, 1); s += __shfl_xor(s, 2);
      s += __shfl_xor(s, 4); s += __shfl_xor(s, 8);
      if (cl == 0) atomicAdd(&rho_raw[rbase + wr + mi * 16 + cg * 4 + r], s);
    }
  if (do_rx) {
#pragma unroll
    for (int i = 0; i < 4; ++i) {
      float s = rx[i];
      s += __shfl_xor(s, 16); s += __shfl_xor(s, 32);
      if (lane < 16) atomicAdd(&rho_raw[rbase + wr + i * 16 + lane], s);
    }
  }
}

// ================= M2 = Wsel @ W2 (fp16 out) + bcat = bsel + b2.Wsel_row ===========
__global__ __launch_bounds__(256) void m2_k(
    const float* __restrict__ Wv, const float* __restrict__ Wt,
    const float* __restrict__ W2, const float* __restrict__ b2,
    const float* __restrict__ bv, const float* __restrict__ bt,
    unsigned short* __restrict__ M2v, unsigned short* __restrict__ M2t,
    float* __restrict__ bcv, float* __restrict__ bct) {
  __shared__ float rowL[512];
  __shared__ float red[4];
  const int b = blockIdx.x, t = threadIdx.x;
  int n; const float* src; unsigned short* dst; const float* badd; float* bdst;
  if (b < 256) { n = b; src = Wv + (long)n * 512; dst = M2v + (long)n * 512; badd = bv; bdst = bcv; }
  else { n = b - 256; src = Wt + (long)n * 512; dst = M2t + (long)n * 512; badd = bt; bdst = bct; }
  rowL[t] = src[t]; rowL[t + 256] = src[t + 256];
  __syncthreads();
  float a0 = 0.f, a1 = 0.f;
  for (int j = 0; j < 512; ++j) {
    float rv = rowL[j];
    a0 += rv * W2[(long)j * 512 + t];
    a1 += rv * W2[(long)j * 512 + t + 256];
  }
  dst[t] = f2h(a0);
  dst[t + 256] = f2h(a1);
  float p = b2[t] * rowL[t] + b2[t + 256] * rowL[t + 256];
  p = wred(p);
  if ((t & 63) == 0) red[t >> 6] = p;
  __syncthreads();
  if (t == 0) bdst[n] = badd[n] + red[0] + red[1] + red[2] + red[3];
}

// ================= folded heads: Out = X@Wx^T + T@Wm^T + bcat (K=1024) =============
// bx<1024: U for entities h,t (N=256, out fp16 Uh/Ut); else theta for r (N=512, THh)
__global__ __launch_bounds__(256, 3) void head_k(
    const float* __restrict__ x0, const float* __restrict__ x1,
    const float* __restrict__ x2, const unsigned short* __restrict__ Tbig,
    const unsigned short* __restrict__ Wvh, const unsigned short* __restrict__ Wth,
    const unsigned short* __restrict__ M2v, const unsigned short* __restrict__ M2t,
    const float* __restrict__ bcv, const float* __restrict__ bct,
    unsigned short* __restrict__ Uh, unsigned short* __restrict__ Ut,
    unsigned short* __restrict__ THh) {
  __shared__ float Af[128 * 64];           // 32 KB (fp32 X phase; low half = fp16 T phase)
  __shared__ unsigned short Bs[128 * 64];  // 16 KB
  unsigned short* As16 = (unsigned short*)Af;
  const int tid = threadIdx.x, lane = tid & 63, w = tid >> 6;
  const int bx = blockIdx.x;
  int ent, n0, ldo; long mloc;
  const float* X; const unsigned short *Wx, *Wm; const float* bias; unsigned short* Out;
  if (bx < 1024) {
    int nt = bx & 1, mt = bx >> 1;
    ent = mt >> 8; mloc = (long)(mt & 255) * 128; n0 = nt * 128; ldo = 256;
    X = ent ? x1 : x0; Wx = Wvh; Wm = M2v; bias = bcv; Out = ent ? Ut : Uh;
  } else {
    int t = bx - 1024, nt = t & 3, mt = t >> 2;
    ent = 2; mloc = (long)mt * 128; n0 = nt * 128; ldo = 512;
    X = x2; Wx = Wth; Wm = M2t; bias = bct; Out = THh;
  }
  const long trow = (long)ent * NB + mloc;
  const int wr = (w >> 1) * 64, wc = (w & 1) * 64;

  const int arow = w * 32 + (lane >> 4), acol = (lane & 15) * 4;
  const float* Ag = X + (mloc + arow) * HH + acol;
  float* Al = Af + arow * 64 + acol;
  const int srow = w * 32 + (lane >> 3), scol = (lane & 7) * 8;
  const unsigned short* Tg = Tbig + (trow + srow) * HH + scol;
  unsigned short* Sl = As16 + srow * 64 + scol;
  const int brow = srow, bcol = scol;
  unsigned short* Bl = Bs + brow * 64 + bcol;

  f32x4 acc[4][4] = {};
  for (int kb = 0; kb < 16; ++kb) {
    const int ko = (kb & 7) * 64;
    if (kb < 8) {
#pragma unroll
      for (int q = 0; q < 8; ++q) gl_lds16(Ag + (long)(4 * q) * HH + ko, Al + (4 * q) * 64);
    } else {
#pragma unroll
      for (int q = 0; q < 4; ++q) gl_lds16(Tg + (long)(8 * q) * HH + ko, Sl + (8 * q) * 64);
    }
    const unsigned short* Bg = ((kb < 8) ? Wx : Wm) + (long)(n0 + brow) * HH + bcol;
#pragma unroll
    for (int q = 0; q < 4; ++q) gl_lds16(Bg + (long)(8 * q) * HH + ko, Bl + (8 * q) * 64);
    __syncthreads();
#pragma unroll
    for (int ks = 0; ks < 2; ++ks) {
      const int kcol = ks * 32 + (lane >> 4) * 8;
      f16x8 af[4], bf[4];
#pragma unroll
      for (int i = 0; i < 4; ++i) {
        if (kb < 8) {
          const float* ap = Af + (wr + i * 16 + (lane & 15)) * 64 + kcol;
          f32x4 a0 = *(const f32x4*)ap, a1 = *(const f32x4*)(ap + 4);
          f16x8 t;
          t[0] = (_Float16)a0[0]; t[1] = (_Float16)a0[1];
          t[2] = (_Float16)a0[2]; t[3] = (_Float16)a0[3];
          t[4] = (_Float16)a1[0]; t[5] = (_Float16)a1[1];
          t[6] = (_Float16)a1[2]; t[7] = (_Float16)a1[3];
          af[i] = t;
        } else {
          af[i] = *(const f16x8*)(As16 + (wr + i * 16 + (lane & 15)) * 64 + kcol);
        }
        bf[i] = *(const f16x8*)(Bs + (wc + i * 16 + (lane & 15)) * 64 + kcol);
      }
#pragma unroll
      for (int i = 0; i < 4; ++i)
#pragma unroll
        for (int j = 0; j < 4; ++j)
          acc[i][j] = __builtin_amdgcn_mfma_f32_16x16x32_f16(af[i], bf[j], acc[i][j], 0, 0, 0);
    }
    __syncthreads();
  }

  const int cg = lane >> 4, cl = lane & 15;
#pragma unroll
  for (int mi = 0; mi < 4; ++mi) {
    const long row0 = mloc + wr + mi * 16 + cg * 4;
#pragma unroll
    for (int ni = 0; ni < 4; ++ni) {
      const int col = n0 + wc + ni * 16 + cl;
      const float bc = bias[col];
#pragma unroll
      for (int r = 0; r < 4; ++r)
        Out[(row0 + r) * (long)ldo + col] = f2h(acc[mi][ni][r] + bc);
    }
  }
}

// ================= Givens chain: wave-parallel linear scan =========================
__device__ __forceinline__ void givens_pass(float v[4], const float c[4],
                                            const float s[4], int lane) {
  float vn3 = __shfl_down(v[0], 1);
  float A = 1.f, Bc = 0.f;
#pragma unroll
  for (int k = 0; k < 4; ++k) {
    float vnext = (k < 3) ? v[k + 1] : vn3;
    bool skip = (lane == 63) && (k == 3);
    if (!skip) { Bc = s[k] * Bc + c[k] * vnext; A = s[k] * A; }
  }
  float iA = A, iB = Bc;
#pragma unroll
  for (int off = 1; off < 64; off <<= 1) {
    float pA = __shfl_up(iA, off);
    float pB = __shfl_up(iB, off);
    if (lane >= off) { iB = iA * pB + iB; iA = iA * pA; }
  }
  float eA = __shfl_up(iA, 1);
  float eB = __shfl_up(iB, 1);
  if (lane == 0) { eA = 1.f; eB = 0.f; }
  float v0g = __shfl(v[0], 0);
  float K = eA * v0g + eB;
  float out[4];
#pragma unroll
  for (int k = 0; k < 4; ++k) {
    float vnext = (k < 3) ? v[k + 1] : vn3;
    bool skip = (lane == 63) && (k == 3);
    if (!skip) {
      out[k] = c[k] * K - s[k] * vnext;
      K = s[k] * K + c[k] * vnext;
    } else out[k] = 0.f;
  }
  float K255 = __shfl(K, 63);
  float c255 = __shfl(c[3], 63);
  float s255 = __shfl(s[3], 63);
  float o0 = __shfl(out[0], 0);
  if (lane == 63) out[3] = c255 * K255 - s255 * o0;
  if (lane == 0) out[0] = s255 * K255 + c255 * o0;
  v[0] = out[0]; v[1] = out[1]; v[2] = out[2]; v[3] = out[3];
}

// ================= final per-row kernel: one wave per row ==========================
__global__ __launch_bounds__(256) void final_k(
    const unsigned short* __restrict__ Uh, const unsigned short* __restrict__ Ut,
    const unsigned short* __restrict__ THh, const float* __restrict__ rho_raw,
    const float* __restrict__ rho_c, const float* __restrict__ sim,
    const float* __restrict__ bre, const float* __restrict__ brr,
    const float* __restrict__ ga_rho, const float* __restrict__ gb_rho,
    const float* __restrict__ ga_phi, const float* __restrict__ gb_phi,
    float* __restrict__ out) {
  const int lane = threadIdx.x & 63;
  const int b = blockIdx.x * 4 + (threadIdx.x >> 6);

  us4v h4 = *(const us4v*)(Uh + (long)b * 256 + lane * 4);
  us4v t4 = *(const us4v*)(Ut + (long)b * 256 + lane * 4);
  us4v a4 = *(const us4v*)(THh + (long)b * 512 + lane * 4);
  us4v b4 = *(const us4v*)(THh + (long)b * 512 + 256 + lane * 4);

  const float PI_F = 3.14159265358979f;
  float vh[4], vt[4], cA[4], sA[4], cB[4], sB[4];
#pragma unroll
  for (int k = 0; k < 4; ++k) {
    vh[k] = h2f(h4[k]); vt[k] = h2f(t4[k]);
    float aa = PI_F * tanh_fast(h2f(a4[k]));
    sA[k] = __sinf(aa); cA[k] = __cosf(aa);
    float ab = PI_F * tanh_fast(h2f(b4[k]));
    sB[k] = __sinf(ab); cB[k] = __cosf(ab);
  }

  float ssq = wred(vh[0] * vh[0] + vh[1] * vh[1] + vh[2] * vh[2] + vh[3] * vh[3]);
  float invh = 1.f / (sqrtf(ssq) + 1e-8f);
  float u[4], v[4];
#pragma unroll
  for (int k = 0; k < 4; ++k) { u[k] = vh[k] * invh; v[k] = u[k]; }

  givens_pass(v, cA, sA, lane);  // rotations 0..255
  givens_pass(v, cB, sB, lane);  // rotations 256..511

  float ssr = wred(v[0] * v[0] + v[1] * v[1] + v[2] * v[2] + v[3] * v[3]);
  float invr = 1.f / (sqrtf(ssr) + 1e-8f);
  float ur[4];
#pragma unroll
  for (int k = 0; k < 4; ++k) ur[k] = v[k] * invr;

  float dt = wred(u[0] * ur[0] + u[1] * ur[1] + u[2] * ur[2] + u[3] * ur[3]);
  dt = fminf(fmaxf(dt, -1.f + 1e-8f), 1.f - 1e-8f);
  float omega = acosf(dt);
  float sino = sqrtf(fmaxf(1.f - dt * dt, 0.f));
  float sb = sim[b];
  float gphi = sigm(ga_phi[0] * sb + gb_phi[0]);
  float s1, s2;
  if (omega > 0.001f) {
    s1 = __sinf((1.f - gphi) * omega) / (sino + 1e-8f);
    s2 = __sinf(gphi * omega) / (sino + 1e-8f);
  } else {
    s1 = 1.f - gphi;
    s2 = gphi;
  }
  float up[4];
#pragma unroll
  for (int k = 0; k < 4; ++k) up[k] = s1 * u[k] + s2 * ur[k];
  float ssp = wred(up[0] * up[0] + up[1] * up[1] + up[2] * up[2] + up[3] * up[3]);
  float invp = 1.f / (sqrtf(ssp) + 1e-8f);
  float sst = wred(vt[0] * vt[0] + vt[1] * vt[1] + vt[2] * vt[2] + vt[3] * vt[3]);
  float invt = 1.f / (sqrtf(sst) + 1e-8f);
  float dp = wred(up[0] * vt[0] + up[1] * vt[1] + up[2] * vt[2] + up[3] * vt[3]) * invp * invt;

  float rh = fminf(fmaxf(softplus_fast(rho_raw[b] + rho_c[0] + bre[0]), 0.f), 9.f);
  float rt = fminf(fmaxf(softplus_fast(rho_raw[NB + b] + rho_c[0] + bre[0]), 0.f), 9.f);
  float dR = rho_raw[2 * NB + b] + rho_c[1] + brr[0];
  float grho = sigm(ga_rho[0] * sb + gb_rho[0]);
  float rp = fminf(fmaxf(rh + dR * grho, 0.f), 9.f);
  float er = __expf(rp), eri = __expf(-rp);
  float et = __expf(rt), eti = __expf(-rt);
  float score = -0.25f * (er + eri) * (et + eti) + 0.25f * (er - eri) * (et - eti) * dp;
  if (lane == 0) out[b] = score;
}

extern "C" void kernel_launch(void* const* d_in, const int* in_sizes, int n_in,
                              void* d_out, int out_size, void* d_ws, size_t ws_size,
                              hipStream_t stream) {
  (void)in_sizes; (void)n_in;
  const float* x0 = (const float*)d_in[0];   // ent_embed (h)
  const float* x2 = (const float*)d_in[1];   // rel_embed (r)
  const float* x1 = (const float*)d_in[2];   // ent_label (t)
  const float* sim = (const float*)d_in[3];
  const float* Wv = (const float*)d_in[4];
  const float* bv = (const float*)d_in[5];
  const float* Wre = (const float*)d_in[6];
  const float* bre = (const float*)d_in[7];
  const float* Wrr = (const float*)d_in[8];
  const float* brr = (const float*)d_in[9];
  const float* Wt = (const float*)d_in[10];
  const float* bt = (const float*)d_in[11];
  const float* ga_rho = (const float*)d_in[12];
  const float* gb_rho = (const float*)d_in[13];
  const float* ga_phi = (const float*)d_in[14];
  const float* gb_phi = (const float*)d_in[15];
  const float* W1 = (const float*)d_in[16];
  const float* b1 = (const float*)d_in[17];
  const float* W2 = (const float*)d_in[18];
  const float* b2 = (const float*)d_in[19];

  const size_t NEEDED = 169745416ULL;
  if (ws_size < NEEDED) {  // clean diagnostic failure instead of OOB fault
    (void)hipMemsetAsync(d_out, 0, (size_t)out_size * sizeof(float), stream);
    return;
  }
  char* ws = (char*)d_ws;
  unsigned short* Tbig = (unsigned short*)ws;               // 96 MB (3*NB x 512 f16)
  unsigned short* Uh = (unsigned short*)(ws + 100663296);   // 16 MB (NB x 256 f16)
  unsigned short* Ut = (unsigned short*)(ws + 117440512);   // 16 MB
  unsigned short* THh = (unsigned short*)(ws + 134217728);  // 32 MB (NB x 512 f16)
  float* rho_raw = (float*)(ws + 167772160);                // 384 KB (3*NB f32)
  unsigned short* W1h = (unsigned short*)(ws + 168165376);  // 512 KB (dead after gemm1)
  unsigned short* Wvh = (unsigned short*)(ws + 168689664);  // 256 KB
  unsigned short* Wth = (unsigned short*)(ws + 168951808);  // 512 KB
  unsigned short* M2v = (unsigned short*)(ws + 169476096);  // 256 KB
  unsigned short* M2t = W1h;                                // alias: written by m2_k AFTER gemm1
  float* w2re = (float*)(ws + 169738240);                   // 2 KB
  float* w2rr = (float*)(ws + 169740288);                   // 2 KB
  float* bcv = (float*)(ws + 169742336);                    // 1 KB
  float* bct = (float*)(ws + 169743360);                    // 2 KB
  float* rho_c = (float*)(ws + 169745408);                  // 8 B

  prep_k<<<dim3(2564), dim3(256), 0, stream>>>(
      W1, Wv, Wt, Wre, Wrr, b2, W2, W1h, Wvh, Wth, rho_raw, w2re, w2rr, rho_c);

  gemm1_k<<<dim3(4, 768), dim3(256), 0, stream>>>(
      x0, x1, x2, W1h, b1, Wre, Wrr, w2re, w2rr, Tbig, rho_raw);

  m2_k<<<dim3(768), dim3(256), 0, stream>>>(Wv, Wt, W2, b2, bv, bt, M2v, M2t, bcv, bct);

  head_k<<<dim3(2048), dim3(256), 0, stream>>>(
      x0, x1, x2, Tbig, Wvh, Wth, M2v, M2t, bcv, bct, Uh, Ut, THh);

  final_k<<<dim3(8192), dim3(256), 0, stream>>>(
      Uh, Ut, THh, rho_raw, rho_c, sim, bre, brr, ga_rho, gb_rho, ga_phi, gb_phi,
      (float*)d_out);
}